// Round 1
// baseline (830.469 us; speedup 1.0000x reference)
//
#include <hip/hip_runtime.h>
#include <stdint.h>

#define T_TOKENS 8192
#define D_DIM 1024
#define H_DIM 2048
#define E_NUM 8

typedef __attribute__((ext_vector_type(8))) short short8;
typedef __attribute__((ext_vector_type(4))) float f32x4;
typedef __attribute__((ext_vector_type(8))) unsigned short u16x8;

__device__ __forceinline__ unsigned short f2bf(float f) {
  union { float f; uint32_t u; } v; v.f = f;
  uint32_t r = (v.u + 0x7fffu + ((v.u >> 16) & 1u)) >> 16;
  return (unsigned short)r;
}

__device__ __forceinline__ void gload16(const void* g, void* l) {
  __builtin_amdgcn_global_load_lds((const __attribute__((address_space(1))) void*)g,
                                   (__attribute__((address_space(3))) void*)l, 16, 0, 0);
}

// ---------------- router: logits (f64 accum), top-2, softmax, counts ----------------
__global__ void router_kernel(const float* __restrict__ x, const float* __restrict__ Wg,
                              int* __restrict__ cnt, int* __restrict__ tok_e01,
                              float* __restrict__ tok_w) {
  __shared__ float wgT[E_NUM * D_DIM];  // 32KB, [e][d]
  int tid = threadIdx.x;
  for (int i = tid; i < D_DIM * E_NUM; i += 256) {
    int d = i >> 3, e = i & 7;
    wgT[e * D_DIM + d] = Wg[i];
  }
  __syncthreads();
  int wid = tid >> 6, lane = tid & 63;
  int t = blockIdx.x * 4 + wid;
  const float* xr = x + (size_t)t * D_DIM;
  double acc[E_NUM];
#pragma unroll
  for (int e = 0; e < E_NUM; e++) acc[e] = 0.0;
  for (int i = 0; i < D_DIM / 64; i++) {
    double xv = (double)xr[i * 64 + lane];
#pragma unroll
    for (int e = 0; e < E_NUM; e++) acc[e] += xv * (double)wgT[e * D_DIM + i * 64 + lane];
  }
#pragma unroll
  for (int e = 0; e < E_NUM; e++) {
    double v = acc[e];
#pragma unroll
    for (int off = 32; off >= 1; off >>= 1) v += __shfl_xor(v, off);
    acc[e] = v;
  }
  if (lane == 0) {
    int e0 = 0; double l0 = acc[0];
#pragma unroll
    for (int e = 1; e < E_NUM; e++) if (acc[e] > l0) { l0 = acc[e]; e0 = e; }
    int e1 = -1; double l1 = -1e300;
#pragma unroll
    for (int e = 0; e < E_NUM; e++) if (e != e0 && acc[e] > l1) { l1 = acc[e]; e1 = e; }
    float z1 = expf((float)(l1 - l0));
    float w0 = 1.f / (1.f + z1);
    float w1 = z1 * w0;
    tok_e01[t] = e0 | (e1 << 8);
    tok_w[2 * t] = w0; tok_w[2 * t + 1] = w1;
    atomicAdd(&cnt[e0], 1);
    atomicAdd(&cnt[e1], 1);
  }
}

__global__ void scan_kernel(const int* __restrict__ cnt, int* __restrict__ offs) {
  if (threadIdx.x == 0) {
    int o = 0;
    for (int e = 0; e < E_NUM; e++) { offs[e] = o; o += cnt[e]; }
    offs[E_NUM] = o;
  }
}

__global__ void assign_kernel(const int* __restrict__ tok_e01, const float* __restrict__ tok_w,
                              const int* __restrict__ offs, int* __restrict__ run,
                              int* __restrict__ pair_tok, float* __restrict__ pair_w) {
  int t = blockIdx.x * 256 + threadIdx.x;
  if (t >= T_TOKENS) return;
  int p = tok_e01[t];
  int e0 = p & 255, e1 = (p >> 8) & 255;
  int pos0 = offs[e0] + atomicAdd(&run[e0], 1);
  pair_tok[pos0] = t; pair_w[pos0] = tok_w[2 * t];
  int pos1 = offs[e1] + atomicAdd(&run[e1], 1);
  pair_tok[pos1] = t; pair_w[pos1] = tok_w[2 * t + 1];
}

// ---------------- casts ----------------
__global__ void cast_x_kernel(const float* __restrict__ x, unsigned short* __restrict__ xb) {
  int i = blockIdx.x * 256 + threadIdx.x;  // 8 elems per thread
  const float4* xp = (const float4*)x;
  float4 a = xp[2 * i], b = xp[2 * i + 1];
  u16x8 r;
  r[0] = f2bf(a.x); r[1] = f2bf(a.y); r[2] = f2bf(a.z); r[3] = f2bf(a.w);
  r[4] = f2bf(b.x); r[5] = f2bf(b.y); r[6] = f2bf(b.z); r[7] = f2bf(b.w);
  *(u16x8*)(xb + (size_t)i * 8) = r;
}

// in: [E][R][C] f32 -> out: [E][C][R] bf16   grid: (C/32, R/32, E), block (32,8)
__global__ void cast_transpose_kernel(const float* __restrict__ in, unsigned short* __restrict__ out,
                                      int R, int C) {
  __shared__ float tile[32][33];
  int e = blockIdx.z;
  const float* src = in + (size_t)e * R * C;
  unsigned short* dst = out + (size_t)e * R * C;
  int c0 = blockIdx.x * 32, r0 = blockIdx.y * 32;
  int tx = threadIdx.x, ty = threadIdx.y;
#pragma unroll
  for (int i = 0; i < 4; i++)
    tile[ty + i * 8][tx] = src[(size_t)(r0 + ty + i * 8) * C + c0 + tx];
  __syncthreads();
#pragma unroll
  for (int i = 0; i < 4; i++)
    dst[(size_t)(c0 + ty + i * 8) * R + r0 + tx] = f2bf(tile[tx][ty + i * 8]);
}

// ---------------- pass A: u=x*W1, v=x*W2, h = swish(u)*v  (gather rows) ----------------
__global__ __launch_bounds__(256, 2) void ffn1_kernel(
    const unsigned short* __restrict__ xb, const unsigned short* __restrict__ W1t,
    const unsigned short* __restrict__ W2t, unsigned short* __restrict__ h_buf,
    const int* __restrict__ pair_tok, const int* __restrict__ cnt, const int* __restrict__ offs) {
  int e = blockIdx.z, mt = blockIdx.x, nt = blockIdx.y;
  int me = cnt[e];
  if (mt * 128 >= me) return;
  int base = offs[e] + mt * 128;
  int valid = me - mt * 128; if (valid > 128) valid = 128;

  __shared__ alignas(16) unsigned short Alds[128 * 32];
  __shared__ alignas(16) unsigned short B1lds[128 * 32];
  __shared__ alignas(16) unsigned short B2lds[128 * 32];

  int tid = threadIdx.x;
  int w = tid >> 6, lane = tid & 63;

  int q0 = w * 64 + lane;        // rows 0..63
  int q1 = q0 + 256;             // rows 64..127
  int row0 = q0 >> 2, kc0 = (q0 & 3) * 16;
  int row1 = q1 >> 2, kc1 = (q1 & 3) * 16;

  int t0 = pair_tok[base + (row0 < valid ? row0 : valid - 1)];
  int t1 = pair_tok[base + (row1 < valid ? row1 : valid - 1)];

  const char* gA0 = (const char*)xb + (size_t)t0 * 2048 + kc0;
  const char* gA1 = (const char*)xb + (size_t)t1 * 2048 + kc1;
  size_t wbase = (size_t)e * H_DIM * D_DIM * 2;
  const char* gB10 = (const char*)W1t + wbase + (size_t)(nt * 128 + row0) * 2048 + kc0;
  const char* gB11 = (const char*)W1t + wbase + (size_t)(nt * 128 + row1) * 2048 + kc1;
  const char* gB20 = (const char*)W2t + wbase + (size_t)(nt * 128 + row0) * 2048 + kc0;
  const char* gB21 = (const char*)W2t + wbase + (size_t)(nt * 128 + row1) * 2048 + kc1;

  char* lA0 = (char*)Alds + w * 1024;
  char* lA1 = (char*)Alds + (w + 4) * 1024;
  char* lB10 = (char*)B1lds + w * 1024;
  char* lB11 = (char*)B1lds + (w + 4) * 1024;
  char* lB20 = (char*)B2lds + w * 1024;
  char* lB21 = (char*)B2lds + (w + 4) * 1024;

  int wr = w >> 1, wc = w & 1, l15 = lane & 15, g = lane >> 4;
  int aoff[4], boff[4];
#pragma unroll
  for (int i = 0; i < 4; i++) {
    aoff[i] = ((wr * 64 + i * 16 + l15) * 32 + g * 8) * 2;
    boff[i] = ((wc * 64 + i * 16 + l15) * 32 + g * 8) * 2;
  }

  f32x4 u[4][4], v[4][4];
#pragma unroll
  for (int i = 0; i < 4; i++)
#pragma unroll
    for (int j = 0; j < 4; j++) { u[i][j] = (f32x4){0.f,0.f,0.f,0.f}; v[i][j] = (f32x4){0.f,0.f,0.f,0.f}; }

  for (int ks = 0; ks < 32; ks++) {
    if (ks) __syncthreads();
    int ko = ks * 64;
    gload16(gA0 + ko, lA0);  gload16(gA1 + ko, lA1);
    gload16(gB10 + ko, lB10); gload16(gB11 + ko, lB11);
    gload16(gB20 + ko, lB20); gload16(gB21 + ko, lB21);
    __syncthreads();
    short8 a[4], b1[4], b2[4];
#pragma unroll
    for (int i = 0; i < 4; i++) {
      a[i]  = *(const short8*)((const char*)Alds  + aoff[i]);
      b1[i] = *(const short8*)((const char*)B1lds + boff[i]);
      b2[i] = *(const short8*)((const char*)B2lds + boff[i]);
    }
#pragma unroll
    for (int i = 0; i < 4; i++)
#pragma unroll
      for (int j = 0; j < 4; j++) {
        u[i][j] = __builtin_amdgcn_mfma_f32_16x16x32_bf16(a[i], b1[j], u[i][j], 0, 0, 0);
        v[i][j] = __builtin_amdgcn_mfma_f32_16x16x32_bf16(a[i], b2[j], v[i][j], 0, 0, 0);
      }
  }

  int colbase = nt * 128 + wc * 64;
#pragma unroll
  for (int i = 0; i < 4; i++) {
    int mrow_base = wr * 64 + i * 16 + g * 4;
#pragma unroll
    for (int j = 0; j < 4; j++) {
      int col = colbase + j * 16 + l15;
#pragma unroll
      for (int r = 0; r < 4; r++) {
        int mrow = mrow_base + r;
        if (mrow < valid) {
          float uu = u[i][j][r], vv = v[i][j][r];
          float hh = (uu / (1.f + __expf(-uu))) * vv;
          h_buf[(size_t)(base + mrow) * H_DIM + col] = f2bf(hh);
        }
      }
    }
  }
}

// ---------------- pass B: y = h*W3, scatter-add weighted ----------------
__global__ __launch_bounds__(256, 2) void ffn2_kernel(
    const unsigned short* __restrict__ h_buf, const unsigned short* __restrict__ W3t,
    const int* __restrict__ pair_tok, const float* __restrict__ pair_w,
    const int* __restrict__ cnt, const int* __restrict__ offs, float* __restrict__ out) {
  int e = blockIdx.z, mt = blockIdx.x, nt = blockIdx.y;
  int me = cnt[e];
  if (mt * 128 >= me) return;
  int base = offs[e] + mt * 128;
  int valid = me - mt * 128; if (valid > 128) valid = 128;

  __shared__ alignas(16) unsigned short Alds[128 * 32];
  __shared__ alignas(16) unsigned short Blds[128 * 32];

  int tid = threadIdx.x, w = tid >> 6, lane = tid & 63;
  int q0 = w * 64 + lane, q1 = q0 + 256;
  int row0 = q0 >> 2, kc0 = (q0 & 3) * 16;
  int row1 = q1 >> 2, kc1 = (q1 & 3) * 16;

  int ar0 = base + (row0 < valid ? row0 : valid - 1);
  int ar1 = base + (row1 < valid ? row1 : valid - 1);
  const char* gA0 = (const char*)h_buf + (size_t)ar0 * 4096 + kc0;
  const char* gA1 = (const char*)h_buf + (size_t)ar1 * 4096 + kc1;
  size_t wbase = (size_t)e * D_DIM * H_DIM * 2;
  const char* gB0 = (const char*)W3t + wbase + (size_t)(nt * 128 + row0) * 4096 + kc0;
  const char* gB1 = (const char*)W3t + wbase + (size_t)(nt * 128 + row1) * 4096 + kc1;

  char* lA0 = (char*)Alds + w * 1024;
  char* lA1 = (char*)Alds + (w + 4) * 1024;
  char* lB0 = (char*)Blds + w * 1024;
  char* lB1 = (char*)Blds + (w + 4) * 1024;

  int wr = w >> 1, wc = w & 1, l15 = lane & 15, g = lane >> 4;
  int aoff[4], boff[4];
#pragma unroll
  for (int i = 0; i < 4; i++) {
    aoff[i] = ((wr * 64 + i * 16 + l15) * 32 + g * 8) * 2;
    boff[i] = ((wc * 64 + i * 16 + l15) * 32 + g * 8) * 2;
  }

  f32x4 acc[4][4];
#pragma unroll
  for (int i = 0; i < 4; i++)
#pragma unroll
    for (int j = 0; j < 4; j++) acc[i][j] = (f32x4){0.f,0.f,0.f,0.f};

  for (int ks = 0; ks < 64; ks++) {
    if (ks) __syncthreads();
    int ko = ks * 64;
    gload16(gA0 + ko, lA0); gload16(gA1 + ko, lA1);
    gload16(gB0 + ko, lB0); gload16(gB1 + ko, lB1);
    __syncthreads();
    short8 a[4], b[4];
#pragma unroll
    for (int i = 0; i < 4; i++) {
      a[i] = *(const short8*)((const char*)Alds + aoff[i]);
      b[i] = *(const short8*)((const char*)Blds + boff[i]);
    }
#pragma unroll
    for (int i = 0; i < 4; i++)
#pragma unroll
      for (int j = 0; j < 4; j++)
        acc[i][j] = __builtin_amdgcn_mfma_f32_16x16x32_bf16(a[i], b[j], acc[i][j], 0, 0, 0);
  }

  int colbase = nt * 128 + wc * 64;
#pragma unroll
  for (int i = 0; i < 4; i++) {
    int mrow_base = wr * 64 + i * 16 + g * 4;
#pragma unroll
    for (int r = 0; r < 4; r++) {
      int mrow = mrow_base + r;
      if (mrow < valid) {
        int pos = base + mrow;
        int tok = pair_tok[pos];
        float wgt = pair_w[pos];
        float* orow = out + (size_t)tok * D_DIM + colbase;
#pragma unroll
        for (int j = 0; j < 4; j++)
          unsafeAtomicAdd(orow + j * 16 + l15, acc[i][j][r] * wgt);
      }
    }
  }
}

// ---------------- launch ----------------
extern "C" void kernel_launch(void* const* d_in, const int* in_sizes, int n_in,
                              void* d_out, int out_size, void* d_ws, size_t ws_size,
                              hipStream_t stream) {
  const float* x  = (const float*)d_in[0];
  const float* Wg = (const float*)d_in[1];
  const float* W1 = (const float*)d_in[2];
  const float* W2 = (const float*)d_in[3];
  const float* W3 = (const float*)d_in[4];
  float* out = (float*)d_out;

  char* ws = (char*)d_ws;
  size_t off = 0;
  auto alloc = [&](size_t bytes) -> char* {
    char* p = ws + off; off += (bytes + 255) & ~(size_t)255; return p;
  };

  int*            cnt      = (int*)alloc(16 * 4);
  int*            offs     = (int*)alloc(16 * 4);
  int*            run      = (int*)alloc(16 * 4);
  int*            tok_e01  = (int*)alloc(T_TOKENS * 4);
  float*          tok_w    = (float*)alloc(T_TOKENS * 8);
  int*            pair_tok = (int*)alloc(2 * T_TOKENS * 4);
  float*          pair_w   = (float*)alloc(2 * T_TOKENS * 4);
  unsigned short* xb       = (unsigned short*)alloc((size_t)T_TOKENS * D_DIM * 2);
  unsigned short* W1t      = (unsigned short*)alloc((size_t)E_NUM * D_DIM * H_DIM * 2);
  unsigned short* W2t      = (unsigned short*)alloc((size_t)E_NUM * D_DIM * H_DIM * 2);
  unsigned short* W3t      = (unsigned short*)alloc((size_t)E_NUM * D_DIM * H_DIM * 2);
  unsigned short* h_buf    = (unsigned short*)alloc((size_t)2 * T_TOKENS * H_DIM * 2);

  hipMemsetAsync(cnt, 0, 16 * 4, stream);
  hipMemsetAsync(run, 0, 16 * 4, stream);
  hipMemsetAsync(out, 0, (size_t)out_size * sizeof(float), stream);

  router_kernel<<<T_TOKENS / 4, 256, 0, stream>>>(x, Wg, cnt, tok_e01, tok_w);
  scan_kernel<<<1, 64, 0, stream>>>(cnt, offs);
  assign_kernel<<<T_TOKENS / 256, 256, 0, stream>>>(tok_e01, tok_w, offs, run, pair_tok, pair_w);
  cast_x_kernel<<<(T_TOKENS * D_DIM / 8) / 256, 256, 0, stream>>>(x, xb);
  dim3 tb(32, 8);
  cast_transpose_kernel<<<dim3(H_DIM / 32, D_DIM / 32, E_NUM), tb, 0, stream>>>(W1, W1t, D_DIM, H_DIM);
  cast_transpose_kernel<<<dim3(H_DIM / 32, D_DIM / 32, E_NUM), tb, 0, stream>>>(W2, W2t, D_DIM, H_DIM);
  cast_transpose_kernel<<<dim3(D_DIM / 32, H_DIM / 32, E_NUM), tb, 0, stream>>>(W3, W3t, H_DIM, D_DIM);

  ffn1_kernel<<<dim3(64, H_DIM / 128, E_NUM), 256, 0, stream>>>(xb, W1t, W2t, h_buf, pair_tok, cnt, offs);
  ffn2_kernel<<<dim3(64, D_DIM / 128, E_NUM), 256, 0, stream>>>(h_buf, W3t, pair_tok, pair_w, cnt, offs, out);
}

// Round 2
// 759.342 us; speedup vs baseline: 1.0937x; 1.0937x over previous
//
#include <hip/hip_runtime.h>
#include <stdint.h>

#define T_TOKENS 8192
#define D_DIM 1024
#define H_DIM 2048
#define E_NUM 8
#define MAXP 17408        // 16384 pairs + up to 8*127 pad, rounded to 128
#define MAXTILES 136      // max sum of per-expert ceil(cnt/128)

typedef __attribute__((ext_vector_type(8))) short short8;
typedef __attribute__((ext_vector_type(4))) float f32x4;
typedef __attribute__((ext_vector_type(8))) unsigned short u16x8;

__device__ __forceinline__ unsigned short f2bf(float f) {
  union { float f; uint32_t u; } v; v.f = f;
  uint32_t r = (v.u + 0x7fffu + ((v.u >> 16) & 1u)) >> 16;
  return (unsigned short)r;
}

__device__ __forceinline__ void gload16(const void* g, void* l) {
  __builtin_amdgcn_global_load_lds((const __attribute__((address_space(1))) void*)g,
                                   (__attribute__((address_space(3))) void*)l, 16, 0, 0);
}

// ---------------- router: logits (f64 accum), top-2, softmax, counts ----------------
__global__ void router_kernel(const float* __restrict__ x, const float* __restrict__ Wg,
                              int* __restrict__ cnt, int* __restrict__ tok_e01,
                              float* __restrict__ tok_w) {
  __shared__ float wgT[E_NUM * D_DIM];  // 32KB, [e][d]
  int tid = threadIdx.x;
  for (int i = tid; i < D_DIM * E_NUM; i += 256) {
    int d = i >> 3, e = i & 7;
    wgT[e * D_DIM + d] = Wg[i];
  }
  __syncthreads();
  int wid = tid >> 6, lane = tid & 63;
  int t = blockIdx.x * 4 + wid;
  const float* xr = x + (size_t)t * D_DIM;
  double acc[E_NUM];
#pragma unroll
  for (int e = 0; e < E_NUM; e++) acc[e] = 0.0;
  for (int i = 0; i < D_DIM / 64; i++) {
    double xv = (double)xr[i * 64 + lane];
#pragma unroll
    for (int e = 0; e < E_NUM; e++) acc[e] += xv * (double)wgT[e * D_DIM + i * 64 + lane];
  }
#pragma unroll
  for (int e = 0; e < E_NUM; e++) {
    double v = acc[e];
#pragma unroll
    for (int off = 32; off >= 1; off >>= 1) v += __shfl_xor(v, off);
    acc[e] = v;
  }
  if (lane == 0) {
    int e0 = 0; double l0 = acc[0];
#pragma unroll
    for (int e = 1; e < E_NUM; e++) if (acc[e] > l0) { l0 = acc[e]; e0 = e; }
    int e1 = -1; double l1 = -1e300;
#pragma unroll
    for (int e = 0; e < E_NUM; e++) if (e != e0 && acc[e] > l1) { l1 = acc[e]; e1 = e; }
    float z1 = expf((float)(l1 - l0));
    float w0 = 1.f / (1.f + z1);
    float w1 = z1 * w0;
    tok_e01[t] = e0 | (e1 << 8);
    tok_w[2 * t] = w0; tok_w[2 * t + 1] = w1;
    atomicAdd(&cnt[e0], 1);
    atomicAdd(&cnt[e1], 1);
  }
}

// padded offsets + static tile table (segments 128-aligned)
__global__ void scan_kernel(const int* __restrict__ cnt, int* __restrict__ poffs,
                            int* __restrict__ tile2e, int* __restrict__ tile_row0) {
  if (threadIdx.x == 0) {
    int po = 0, tf = 0;
    for (int e = 0; e < E_NUM; e++) {
      poffs[e] = po;
      int nt = (cnt[e] + 127) >> 7;
      for (int i = 0; i < nt; i++) { tile2e[tf] = e; tile_row0[tf] = po + i * 128; tf++; }
      po += nt << 7;
    }
    for (; tf < MAXTILES; tf++) { tile2e[tf] = -1; tile_row0[tf] = 0; }
  }
}

__global__ void assign_kernel(const int* __restrict__ tok_e01, const float* __restrict__ tok_w,
                              const int* __restrict__ poffs, int* __restrict__ run,
                              int* __restrict__ pair_tok, float* __restrict__ pair_w) {
  int t = blockIdx.x * 256 + threadIdx.x;
  if (t >= T_TOKENS) return;
  int p = tok_e01[t];
  int e0 = p & 255, e1 = (p >> 8) & 255;
  int pos0 = poffs[e0] + atomicAdd(&run[e0], 1);
  pair_tok[pos0] = t; pair_w[pos0] = tok_w[2 * t];
  int pos1 = poffs[e1] + atomicAdd(&run[e1], 1);
  pair_tok[pos1] = t; pair_w[pos1] = tok_w[2 * t + 1];
}

// ---------------- casts ----------------
__global__ void cast_x_kernel(const float* __restrict__ x, unsigned short* __restrict__ xb) {
  int i = blockIdx.x * 256 + threadIdx.x;  // 8 elems per thread
  const float4* xp = (const float4*)x;
  float4 a = xp[2 * i], b = xp[2 * i + 1];
  u16x8 r;
  r[0] = f2bf(a.x); r[1] = f2bf(a.y); r[2] = f2bf(a.z); r[3] = f2bf(a.w);
  r[4] = f2bf(b.x); r[5] = f2bf(b.y); r[6] = f2bf(b.z); r[7] = f2bf(b.w);
  *(u16x8*)(xb + (size_t)i * 8) = r;
}

// in: [E][R][C] f32 -> out: [E][C][R] bf16   grid: (C/32, R/32, E), block (32,8)
__global__ void cast_transpose_kernel(const float* __restrict__ in, unsigned short* __restrict__ out,
                                      int R, int C) {
  __shared__ float tile[32][33];
  int e = blockIdx.z;
  const float* src = in + (size_t)e * R * C;
  unsigned short* dst = out + (size_t)e * R * C;
  int c0 = blockIdx.x * 32, r0 = blockIdx.y * 32;
  int tx = threadIdx.x, ty = threadIdx.y;
#pragma unroll
  for (int i = 0; i < 4; i++)
    tile[ty + i * 8][tx] = src[(size_t)(r0 + ty + i * 8) * C + c0 + tx];
  __syncthreads();
#pragma unroll
  for (int i = 0; i < 4; i++)
    dst[(size_t)(c0 + ty + i * 8) * R + r0 + tx] = f2bf(tile[tx][ty + i * 8]);
}

// ---------------- pass A: u=x*W1, v=x*W2, h = swish(u)*v  (2-phase dbuf) ----------------
__global__ __launch_bounds__(256, 2) void ffn1_kernel(
    const unsigned short* __restrict__ xb, const unsigned short* __restrict__ W1t,
    const unsigned short* __restrict__ W2t, unsigned short* __restrict__ h_buf,
    const int* __restrict__ pair_tok, const int* __restrict__ tile2e,
    const int* __restrict__ tile_row0) {
  const int NWG = MAXTILES * (H_DIM / 128);  // 2176, %8==0
  int orig = blockIdx.x;
  int xcd = orig & 7, idx = orig >> 3;
  int wg = xcd * (NWG >> 3) + idx;           // bijective XCD-chunked swizzle
  int f = wg >> 4;                            // tile index (16 N-tiles)
  int nt = wg & 15;
  int e = tile2e[f];
  if (e < 0) return;
  int row0 = tile_row0[f];

  __shared__ alignas(16) unsigned short Alds[2][128 * 32];
  __shared__ alignas(16) unsigned short B1lds[2][128 * 32];
  __shared__ alignas(16) unsigned short B2lds[2][128 * 32];

  int tid = threadIdx.x;
  int w = tid >> 6, lane = tid & 63;

  int q0 = w * 64 + lane;        // LDS rows 0..63
  int q1 = q0 + 256;             // LDS rows 64..127
  int r0_ = q0 >> 2, kc0 = (q0 & 3) * 16;
  int r1_ = q1 >> 2, kc1 = (q1 & 3) * 16;

  int t0 = pair_tok[row0 + r0_];
  int t1 = pair_tok[row0 + r1_];

  const char* gA0 = (const char*)xb + (size_t)t0 * 2048 + kc0;
  const char* gA1 = (const char*)xb + (size_t)t1 * 2048 + kc1;
  size_t wbase = (size_t)e * H_DIM * D_DIM * 2;
  const char* gB10 = (const char*)W1t + wbase + (size_t)(nt * 128 + r0_) * 2048 + kc0;
  const char* gB11 = (const char*)W1t + wbase + (size_t)(nt * 128 + r1_) * 2048 + kc1;
  const char* gB20 = (const char*)W2t + wbase + (size_t)(nt * 128 + r0_) * 2048 + kc0;
  const char* gB21 = (const char*)W2t + wbase + (size_t)(nt * 128 + r1_) * 2048 + kc1;

  auto stage = [&](int buf, int ks) {
    int ko = ks * 64;
    char* la = (char*)(&Alds[buf][0]);
    char* l1 = (char*)(&B1lds[buf][0]);
    char* l2 = (char*)(&B2lds[buf][0]);
    gload16(gA0 + ko, la + w * 1024);
    gload16(gA1 + ko, la + (w + 4) * 1024);
    gload16(gB10 + ko, l1 + w * 1024);
    gload16(gB11 + ko, l1 + (w + 4) * 1024);
    gload16(gB20 + ko, l2 + w * 1024);
    gload16(gB21 + ko, l2 + (w + 4) * 1024);
  };

  int wr = w >> 1, wc = w & 1, l15 = lane & 15, g = lane >> 4;
  int aoff[4], boff[4];
#pragma unroll
  for (int i = 0; i < 4; i++) {
    aoff[i] = ((wr * 64 + i * 16 + l15) * 32 + g * 8) * 2;
    boff[i] = ((wc * 64 + i * 16 + l15) * 32 + g * 8) * 2;
  }

  f32x4 u[4][4], v[4][4];
#pragma unroll
  for (int i = 0; i < 4; i++)
#pragma unroll
    for (int j = 0; j < 4; j++) { u[i][j] = (f32x4){0.f,0.f,0.f,0.f}; v[i][j] = (f32x4){0.f,0.f,0.f,0.f}; }

  const int NK = 32;
  stage(0, 0);
  __syncthreads();
  for (int ks = 0; ks < NK; ks++) {
    int cur = ks & 1;
    if (ks + 1 < NK) stage(cur ^ 1, ks + 1);   // issue next-tile loads BEFORE compute
    const char* ab = (const char*)(&Alds[cur][0]);
    const char* b1b = (const char*)(&B1lds[cur][0]);
    const char* b2b = (const char*)(&B2lds[cur][0]);
    short8 a[4], b1[4], b2[4];
#pragma unroll
    for (int i = 0; i < 4; i++) {
      a[i]  = *(const short8*)(ab  + aoff[i]);
      b1[i] = *(const short8*)(b1b + boff[i]);
      b2[i] = *(const short8*)(b2b + boff[i]);
    }
#pragma unroll
    for (int i = 0; i < 4; i++)
#pragma unroll
      for (int j = 0; j < 4; j++) {
        u[i][j] = __builtin_amdgcn_mfma_f32_16x16x32_bf16(a[i], b1[j], u[i][j], 0, 0, 0);
        v[i][j] = __builtin_amdgcn_mfma_f32_16x16x32_bf16(a[i], b2[j], v[i][j], 0, 0, 0);
      }
    if (ks + 1 < NK) __syncthreads();          // one barrier per K-step
  }

  int colbase = nt * 128 + wc * 64;
#pragma unroll
  for (int i = 0; i < 4; i++) {
    int mrow_base = wr * 64 + i * 16 + g * 4;
#pragma unroll
    for (int j = 0; j < 4; j++) {
      int col = colbase + j * 16 + l15;
#pragma unroll
      for (int r = 0; r < 4; r++) {
        int mrow = mrow_base + r;
        float uu = u[i][j][r], vv = v[i][j][r];
        float hh = (uu / (1.f + __expf(-uu))) * vv;
        h_buf[(size_t)(row0 + mrow) * H_DIM + col] = f2bf(hh);
      }
    }
  }
}

// ---------------- pass B: y = h*W3, scatter-add weighted (2-phase dbuf) ----------------
__global__ __launch_bounds__(256, 2) void ffn2_kernel(
    const unsigned short* __restrict__ h_buf, const unsigned short* __restrict__ W3t,
    const int* __restrict__ pair_tok, const float* __restrict__ pair_w,
    const int* __restrict__ tile2e, const int* __restrict__ tile_row0,
    float* __restrict__ out) {
  const int NWG = MAXTILES * (D_DIM / 128);  // 1088, %8==0
  int orig = blockIdx.x;
  int xcd = orig & 7, idx = orig >> 3;
  int wg = xcd * (NWG >> 3) + idx;
  int f = wg >> 3;                            // tile index (8 N-tiles)
  int nt = wg & 7;
  int e = tile2e[f];
  if (e < 0) return;
  int row0 = tile_row0[f];

  __shared__ alignas(16) unsigned short Alds[2][128 * 32];
  __shared__ alignas(16) unsigned short Blds[2][128 * 32];

  int tid = threadIdx.x, w = tid >> 6, lane = tid & 63;
  int q0 = w * 64 + lane, q1 = q0 + 256;
  int r0_ = q0 >> 2, kc0 = (q0 & 3) * 16;
  int r1_ = q1 >> 2, kc1 = (q1 & 3) * 16;

  const char* gA0 = (const char*)h_buf + (size_t)(row0 + r0_) * 4096 + kc0;
  const char* gA1 = (const char*)h_buf + (size_t)(row0 + r1_) * 4096 + kc1;
  size_t wbase = (size_t)e * D_DIM * H_DIM * 2;
  const char* gB0 = (const char*)W3t + wbase + (size_t)(nt * 128 + r0_) * 4096 + kc0;
  const char* gB1 = (const char*)W3t + wbase + (size_t)(nt * 128 + r1_) * 4096 + kc1;

  auto stage = [&](int buf, int ks) {
    int ko = ks * 64;
    char* la = (char*)(&Alds[buf][0]);
    char* lb = (char*)(&Blds[buf][0]);
    gload16(gA0 + ko, la + w * 1024);
    gload16(gA1 + ko, la + (w + 4) * 1024);
    gload16(gB0 + ko, lb + w * 1024);
    gload16(gB1 + ko, lb + (w + 4) * 1024);
  };

  int wr = w >> 1, wc = w & 1, l15 = lane & 15, g = lane >> 4;
  int aoff[4], boff[4];
#pragma unroll
  for (int i = 0; i < 4; i++) {
    aoff[i] = ((wr * 64 + i * 16 + l15) * 32 + g * 8) * 2;
    boff[i] = ((wc * 64 + i * 16 + l15) * 32 + g * 8) * 2;
  }

  f32x4 acc[4][4];
#pragma unroll
  for (int i = 0; i < 4; i++)
#pragma unroll
    for (int j = 0; j < 4; j++) acc[i][j] = (f32x4){0.f,0.f,0.f,0.f};

  const int NK = 64;
  stage(0, 0);
  __syncthreads();
  for (int ks = 0; ks < NK; ks++) {
    int cur = ks & 1;
    if (ks + 1 < NK) stage(cur ^ 1, ks + 1);
    const char* ab = (const char*)(&Alds[cur][0]);
    const char* bb = (const char*)(&Blds[cur][0]);
    short8 a[4], b[4];
#pragma unroll
    for (int i = 0; i < 4; i++) {
      a[i] = *(const short8*)(ab + aoff[i]);
      b[i] = *(const short8*)(bb + boff[i]);
    }
#pragma unroll
    for (int i = 0; i < 4; i++)
#pragma unroll
      for (int j = 0; j < 4; j++)
        acc[i][j] = __builtin_amdgcn_mfma_f32_16x16x32_bf16(a[i], b[j], acc[i][j], 0, 0, 0);
    if (ks + 1 < NK) __syncthreads();
  }

  int colbase = nt * 128 + wc * 64;
#pragma unroll
  for (int i = 0; i < 4; i++) {
    int mrow_base = wr * 64 + i * 16 + g * 4;
#pragma unroll
    for (int r = 0; r < 4; r++) {
      int mrow = mrow_base + r;
      int pos = row0 + mrow;
      int tok = pair_tok[pos];
      float wgt = pair_w[pos];
      float* orow = out + (size_t)tok * D_DIM + colbase;
#pragma unroll
      for (int j = 0; j < 4; j++)
        unsafeAtomicAdd(orow + j * 16 + l15, acc[i][j][r] * wgt);
    }
  }
}

// ---------------- launch ----------------
extern "C" void kernel_launch(void* const* d_in, const int* in_sizes, int n_in,
                              void* d_out, int out_size, void* d_ws, size_t ws_size,
                              hipStream_t stream) {
  const float* x  = (const float*)d_in[0];
  const float* Wg = (const float*)d_in[1];
  const float* W1 = (const float*)d_in[2];
  const float* W2 = (const float*)d_in[3];
  const float* W3 = (const float*)d_in[4];
  float* out = (float*)d_out;

  char* ws = (char*)d_ws;
  size_t off = 0;
  auto alloc = [&](size_t bytes) -> char* {
    char* p = ws + off; off += (bytes + 255) & ~(size_t)255; return p;
  };

  int*            cnt       = (int*)alloc(16 * 4);
  int*            poffs     = (int*)alloc(16 * 4);
  int*            run       = (int*)alloc(16 * 4);
  int*            tile2e    = (int*)alloc(MAXTILES * 4);
  int*            tile_row0 = (int*)alloc(MAXTILES * 4);
  int*            tok_e01   = (int*)alloc(T_TOKENS * 4);
  float*          tok_w     = (float*)alloc(T_TOKENS * 8);
  int*            pair_tok  = (int*)alloc(MAXP * 4);
  float*          pair_w    = (float*)alloc(MAXP * 4);
  unsigned short* xb        = (unsigned short*)alloc((size_t)T_TOKENS * D_DIM * 2);
  unsigned short* W1t       = (unsigned short*)alloc((size_t)E_NUM * D_DIM * H_DIM * 2);
  unsigned short* W2t       = (unsigned short*)alloc((size_t)E_NUM * D_DIM * H_DIM * 2);
  unsigned short* W3t       = (unsigned short*)alloc((size_t)E_NUM * D_DIM * H_DIM * 2);
  unsigned short* h_buf     = (unsigned short*)alloc((size_t)MAXP * H_DIM * 2);

  hipMemsetAsync(cnt, 0, 16 * 4, stream);
  hipMemsetAsync(run, 0, 16 * 4, stream);
  hipMemsetAsync(pair_tok, 0, MAXP * 4, stream);
  hipMemsetAsync(pair_w, 0, MAXP * 4, stream);
  hipMemsetAsync(out, 0, (size_t)out_size * sizeof(float), stream);

  router_kernel<<<T_TOKENS / 4, 256, 0, stream>>>(x, Wg, cnt, tok_e01, tok_w);
  scan_kernel<<<1, 64, 0, stream>>>(cnt, poffs, tile2e, tile_row0);
  assign_kernel<<<T_TOKENS / 256, 256, 0, stream>>>(tok_e01, tok_w, poffs, run, pair_tok, pair_w);
  cast_x_kernel<<<(T_TOKENS * D_DIM / 8) / 256, 256, 0, stream>>>(x, xb);
  dim3 tb(32, 8);
  cast_transpose_kernel<<<dim3(H_DIM / 32, D_DIM / 32, E_NUM), tb, 0, stream>>>(W1, W1t, D_DIM, H_DIM);
  cast_transpose_kernel<<<dim3(H_DIM / 32, D_DIM / 32, E_NUM), tb, 0, stream>>>(W2, W2t, D_DIM, H_DIM);
  cast_transpose_kernel<<<dim3(D_DIM / 32, H_DIM / 32, E_NUM), tb, 0, stream>>>(W3, W3t, H_DIM, D_DIM);

  ffn1_kernel<<<dim3(MAXTILES * (H_DIM / 128)), 256, 0, stream>>>(xb, W1t, W2t, h_buf, pair_tok, tile2e, tile_row0);
  ffn2_kernel<<<dim3(MAXTILES * (D_DIM / 128)), 256, 0, stream>>>(h_buf, W3t, pair_tok, pair_w, tile2e, tile_row0, out);
}